// Round 1
// baseline (758.020 us; speedup 1.0000x reference)
//
#include <hip/hip_runtime.h>
#include <math.h>

#define NTOK   1000000
#define NFEAT  128
#define NCLUS  64
#define TT     64                 // tokens per tile
#define NTILES (NTOK / TT)        // 15625
#define GRID_A 512                // persistent blocks (2 per CU)

// ---------------------------------------------------------------------------
// Kernel 1: per-block partial argmin of d2[n,k] = x2[n] + c2[k] - 2*<x[n],c[k]>
// over the token axis, for all 64 clusters.
// ---------------------------------------------------------------------------
__global__ __launch_bounds__(256, 2)
void cluster_part_kernel(const float* __restrict__ x, const float* __restrict__ cc,
                         float* __restrict__ pv, int* __restrict__ pi)
{
    __shared__ float cs[NFEAT][NCLUS];   // 32 KB, feature-major cluster centers
    __shared__ float xs[NFEAT][TT];      // 32 KB, feature-major token tile

    const int tid  = threadIdx.x;
    const int tx   = tid & 15;    // cluster group: clusters 4*tx..4*tx+3
    const int ty   = tid >> 4;    // token group:   tokens   4*ty..4*ty+3
    const int lsub = tid & 3;     // quarter-row within staging
    const int row  = tid >> 2;    // token/cluster index during staging, 0..63

    // ---- stage cluster centers (transpose to feature-major) + c2 ----
    float c2part = 0.f;
    {
        const float* src = cc + row * NFEAT;
        #pragma unroll
        for (int r = 0; r < 8; ++r) {
            int f = (lsub + 4 * r) * 4;
            float4 v = *(const float4*)(src + f);
            cs[f + 0][row] = v.x; cs[f + 1][row] = v.y;
            cs[f + 2][row] = v.z; cs[f + 3][row] = v.w;
            c2part = fmaf(v.x, v.x, c2part);
            c2part = fmaf(v.y, v.y, c2part);
            c2part = fmaf(v.z, v.z, c2part);
            c2part = fmaf(v.w, v.w, c2part);
        }
        c2part += __shfl_xor(c2part, 1);
        c2part += __shfl_xor(c2part, 2);   // all 4 lanes of group hold c2[row]
    }
    // park c2 in xs[0][0..63] so every thread can grab its 4 clusters' c2
    if (lsub == 0) xs[0][row] = c2part;
    __syncthreads();
    float c2r[4];
    #pragma unroll
    for (int j = 0; j < 4; ++j) c2r[j] = xs[0][tx * 4 + j];
    // (loop-top barrier protects xs before first overwrite)

    float bestv[4]; int besti[4];
    #pragma unroll
    for (int j = 0; j < 4; ++j) { bestv[j] = INFINITY; besti[j] = 0; }

    for (int tile = blockIdx.x; tile < NTILES; tile += GRID_A) {
        __syncthreads();
        // ---- stage x tile (transpose to feature-major) + x2 on the fly ----
        float x2tot;
        {
            const float* src = x + (size_t)(tile * TT + row) * NFEAT;
            float s = 0.f;
            #pragma unroll
            for (int r = 0; r < 8; ++r) {
                int f = (lsub + 4 * r) * 4;
                float4 v = *(const float4*)(src + f);
                xs[f + 0][row] = v.x; xs[f + 1][row] = v.y;
                xs[f + 2][row] = v.z; xs[f + 3][row] = v.w;
                s = fmaf(v.x, v.x, s);
                s = fmaf(v.y, v.y, s);
                s = fmaf(v.z, v.z, s);
                s = fmaf(v.w, v.w, s);
            }
            s += __shfl_xor(s, 1);
            s += __shfl_xor(s, 2);   // full x2 of token `row` in all 4 lanes
            x2tot = s;
        }
        __syncthreads();

        // x2 for my 4 compute tokens lives in my own wave: intra-wave shuffle.
        // token 4*ty+i -> within-wave token (ty&3)*4+i -> lane 4*that
        float x2r[4];
        #pragma unroll
        for (int i = 0; i < 4; ++i)
            x2r[i] = __shfl(x2tot, ((ty & 3) * 4 + i) * 4, 64);

        float acc[4][4];
        #pragma unroll
        for (int i = 0; i < 4; ++i)
            #pragma unroll
            for (int j = 0; j < 4; ++j) acc[i][j] = 0.f;

        #pragma unroll 8
        for (int k = 0; k < NFEAT; ++k) {
            float4 xv = *(const float4*)&xs[k][ty * 4];   // ds_read_b128
            float4 cv = *(const float4*)&cs[k][tx * 4];   // ds_read_b128
            acc[0][0] = fmaf(xv.x, cv.x, acc[0][0]);
            acc[0][1] = fmaf(xv.x, cv.y, acc[0][1]);
            acc[0][2] = fmaf(xv.x, cv.z, acc[0][2]);
            acc[0][3] = fmaf(xv.x, cv.w, acc[0][3]);
            acc[1][0] = fmaf(xv.y, cv.x, acc[1][0]);
            acc[1][1] = fmaf(xv.y, cv.y, acc[1][1]);
            acc[1][2] = fmaf(xv.y, cv.z, acc[1][2]);
            acc[1][3] = fmaf(xv.y, cv.w, acc[1][3]);
            acc[2][0] = fmaf(xv.z, cv.x, acc[2][0]);
            acc[2][1] = fmaf(xv.z, cv.y, acc[2][1]);
            acc[2][2] = fmaf(xv.z, cv.z, acc[2][2]);
            acc[2][3] = fmaf(xv.z, cv.w, acc[2][3]);
            acc[3][0] = fmaf(xv.w, cv.x, acc[3][0]);
            acc[3][1] = fmaf(xv.w, cv.y, acc[3][1]);
            acc[3][2] = fmaf(xv.w, cv.z, acc[3][2]);
            acc[3][3] = fmaf(xv.w, cv.w, acc[3][3]);
        }

        const int nbase = tile * TT + ty * 4;
        #pragma unroll
        for (int i = 0; i < 4; ++i) {
            #pragma unroll
            for (int j = 0; j < 4; ++j) {
                float s = (x2r[i] + c2r[j]) - 2.0f * acc[i][j];
                // strict < keeps the earliest token (n ascends per thread)
                if (s < bestv[j]) { bestv[j] = s; besti[j] = nbase + i; }
            }
        }
    }

    // ---- block-level reduction across the 16 ty-groups per cluster ----
    __syncthreads();
    float* rv = &xs[0][0];          // [64 clusters][16 ty]
    int*   ri = (int*)&cs[0][0];
    #pragma unroll
    for (int j = 0; j < 4; ++j) {
        rv[(tx * 4 + j) * 16 + ty] = bestv[j];
        ri[(tx * 4 + j) * 16 + ty] = besti[j];
    }
    __syncthreads();
    if (tid < NCLUS) {
        float bv = rv[tid * 16]; int bi = ri[tid * 16];
        #pragma unroll
        for (int t = 1; t < 16; ++t) {
            float v = rv[tid * 16 + t]; int ii = ri[tid * 16 + t];
            if (v < bv || (v == bv && ii < bi)) { bv = v; bi = ii; }
        }
        pv[blockIdx.x * NCLUS + tid] = bv;
        pi[blockIdx.x * NCLUS + tid] = bi;
    }
}

// ---------------------------------------------------------------------------
// Kernel 2: final reduce over GRID_A partials per cluster + gather x[best]
// ---------------------------------------------------------------------------
__global__ __launch_bounds__(256)
void cluster_final_kernel(const float* __restrict__ x,
                          const float* __restrict__ pv, const int* __restrict__ pi,
                          float* __restrict__ out)
{
    const int c   = blockIdx.x;    // cluster 0..63
    const int tid = threadIdx.x;
    __shared__ float sv[256];
    __shared__ int   si[256];

    float bv = INFINITY; int bi = 0;
    for (int b = tid; b < GRID_A; b += 256) {
        float v = pv[b * NCLUS + c]; int ii = pi[b * NCLUS + c];
        if (v < bv || (v == bv && ii < bi)) { bv = v; bi = ii; }
    }
    sv[tid] = bv; si[tid] = bi;
    __syncthreads();
    for (int s = 128; s > 0; s >>= 1) {
        if (tid < s) {
            float v = sv[tid + s]; int ii = si[tid + s];
            if (v < sv[tid] || (v == sv[tid] && ii < si[tid])) {
                sv[tid] = v; si[tid] = ii;
            }
        }
        __syncthreads();
    }
    const int best = si[0];
    if (tid < NFEAT) out[c * NFEAT + tid] = x[(size_t)best * NFEAT + tid];
}

extern "C" void kernel_launch(void* const* d_in, const int* in_sizes, int n_in,
                              void* d_out, int out_size, void* d_ws, size_t ws_size,
                              hipStream_t stream) {
    const float* x  = (const float*)d_in[0];   // (1, 1000000, 128) f32
    const float* cc = (const float*)d_in[1];   // (64, 128) f32
    float* out = (float*)d_out;                // (1, 64, 128) f32

    float* pv = (float*)d_ws;                              // GRID_A*64 floats
    int*   pi = (int*)((char*)d_ws + (size_t)GRID_A * NCLUS * sizeof(float));

    cluster_part_kernel<<<GRID_A, 256, 0, stream>>>(x, cc, pv, pi);
    cluster_final_kernel<<<NCLUS, 256, 0, stream>>>(x, pv, pi, out);
}